// Round 13
// baseline (316.519 us; speedup 1.0000x reference)
//
#include <hip/hip_runtime.h>
#include <math.h>

// Mamba block fwd: B=2, L=2048, d_model=1024, d_inner=2048, d_state=16,
// d_conv=4, dt_rank=64.  GEMMs in f16 MFMA, scan fp32 chunked 2-pass.
// Round 13: GEMM1 XCD-cluster block decode (round-12 FETCH=41MB vs 16.8
// unique); f16 split-K partials for gemm3 (halves partial traffic); compact
// dt/bc reduce outputs.
#define MB_B      2
#define MB_L      2048
#define MB_DMODEL 1024
#define MB_DINNER 2048
#define MB_DSTATE 16
#define MB_DTRANK 64
#define MB_ROWS   (MB_B * MB_L)      // 4096
#define MB_E2     (2 * MB_DINNER)    // 4096
#define SC_NC     32                 // scan chunks
#define SC_CHUNK  (MB_L / SC_NC)     // 64 steps per chunk
#define SC_CL     32                 // staging window (steps)
#define SC_CB     64                 // channels per scan block
#define CV_R      4                  // conv rows per thread

typedef _Float16 f16;
typedef __attribute__((ext_vector_type(2))) _Float16 half2v;
typedef __attribute__((ext_vector_type(4))) _Float16 half4;
typedef __attribute__((ext_vector_type(8))) _Float16 half8;
typedef __attribute__((ext_vector_type(4))) float floatx4;

__device__ __forceinline__ float softplus_f(float x) {
    return (x > 20.f) ? x : log1pf(expf(x));
}
__device__ __forceinline__ float silu_f(float x) {
    return x / (1.f + expf(-x));
}

#if __has_builtin(__builtin_amdgcn_exp2f)
__device__ __forceinline__ float exp2_fast(float x) {
    return __builtin_amdgcn_exp2f(x);
}
#else
__device__ __forceinline__ float exp2_fast(float x) {
    return __expf(0.69314718056f * x);
}
#endif

// async global->LDS, 16B/lane. LDS dst is WAVE-UNIFORM base; HW adds lane*16.
typedef const __attribute__((address_space(1))) unsigned char gbyte;
typedef __attribute__((address_space(3))) unsigned char lbyte;
__device__ __forceinline__ void gl_lds16(const void* g, void* l) {
    __builtin_amdgcn_global_load_lds((gbyte*)g, (lbyte*)l, 16, 0, 0);
}

// VALU cross-lane add via DPP.  0xB1 = quad xor1, 0x4E = quad xor2.
template <int CTRL>
__device__ __forceinline__ float dpp_add(float x) {
    int xi = __builtin_bit_cast(int, x);
    int yi = __builtin_amdgcn_update_dpp(0, xi, CTRL, 0xF, 0xF, true);
    return x + __builtin_bit_cast(float, yi);
}

// ---------------------------------------------------------------------------
// Single fused fp32 -> f16 convert over all weight/activation segments.
// ---------------------------------------------------------------------------
__global__ __launch_bounds__(256) void convert_all_kernel(
    const float* __restrict__ x, const float* __restrict__ W_in,
    const float* __restrict__ W_xproj, const float* __restrict__ W_dt,
    const float* __restrict__ W_out, f16* __restrict__ dst)
{
    const int i = (blockIdx.x * 256 + threadIdx.x) * 8;  // < 10878976
    const float* src;
    int local, nsrc;
    if (i < 4194304)      { src = x;       local = i;           nsrc = 4194304; }
    else if (i < 8388608) { src = W_in;    local = i - 4194304; nsrc = 4194304; }
    else if (i < 8650752) { src = W_xproj; local = i - 8388608; nsrc = 196608; }
    else if (i < 8781824) { src = W_dt;    local = i - 8650752; nsrc = 131072; }
    else                  { src = W_out;   local = i - 8781824; nsrc = 2097152; }
    half8 o;
    if (local < nsrc) {
        const float4 a = *reinterpret_cast<const float4*>(src + local);
        const float4 b = *reinterpret_cast<const float4*>(src + local + 4);
        o[0] = (f16)a.x; o[1] = (f16)a.y; o[2] = (f16)a.z; o[3] = (f16)a.w;
        o[4] = (f16)b.x; o[5] = (f16)b.y; o[6] = (f16)b.z; o[7] = (f16)b.w;
    } else {
#pragma unroll
        for (int j = 0; j < 8; j++) o[j] = (f16)0.f;
    }
    *reinterpret_cast<half8*>(dst + i) = o;
}

// ---------------------------------------------------------------------------
// f16 MFMA GEMM, BK=64:  C[m][n] = sum_k A[m][k]*B[n][k]  (C = A·B^T)
// Block tile BM x 128, 4 waves in (4/GN) x GN grid.  XOR swizzle (128-B
// rows): global k-chunk g at stored position p obeys g = p ^ (row&7).
// Per-iteration global advance stepA/stepB (elements) generalizes the
// K-walk.  CMLOG >= 0: 1D grid with XCD-cluster decode — XCD j (= linear
// id % 8, m09) owns 2^CMLOG contiguous M-tiles x all N-tiles, so A-tiles
// stay hot in its private L2 (round-12 GEMM1 FETCH was 2.4x unique).
// EPI==1: v = softplus(v + bias[n]).
// ---------------------------------------------------------------------------
template <typename OutT, int EPI, int BM, int GN, int CMLOG>
__global__ __launch_bounds__(256) void gemm_mfma(
    const f16* __restrict__ A, int lda,
    const f16* __restrict__ B, int ldb,
    OutT* __restrict__ C, int ldc, int kiters, long stepA, long stepB,
    const float* __restrict__ bias)
{
    constexpr int BN = 128;
    constexpr int GM = 4 / GN;
    constexpr int WM = BM / GM;       // wave tile rows
    constexpr int WN = BN / GN;       // wave tile cols
    constexpr int MT = WM / 16, NT = WN / 16;
    constexpr int CPW = (BM + BN) / 32;   // 8-row staging chunks per wave

    __shared__ f16 As[BM * 64];   // [row][k], row stride 64 halves (128 B)
    __shared__ f16 Bs[BN * 64];

    const int tid  = threadIdx.x;
    const int lane = tid & 63;
    const int wave = tid >> 6;
    const int wr   = wave / GN, wc = wave % GN;

    int bxi, byi;
    if constexpr (CMLOG >= 0) {
        const int n = blockIdx.x;
        byi = ((n & 7) << CMLOG) | ((n >> 3) & ((1 << CMLOG) - 1));
        bxi = n >> (3 + CMLOG);
    } else {
        bxi = blockIdx.x; byi = blockIdx.y;
    }
    const int bm = byi * BM, bn = bxi * BN;

    floatx4 zero4 = {0.f, 0.f, 0.f, 0.f};
    floatx4 acc[MT][NT];
#pragma unroll
    for (int i = 0; i < MT; i++)
#pragma unroll
        for (int j = 0; j < NT; j++) acc[i][j] = zero4;

    const int srow = lane >> 3;
    const int scol = ((lane & 7) ^ (srow & 7)) * 8;
    const f16* gp[CPW];
    f16* lp[CPW];
    long stp[CPW];
#pragma unroll
    for (int i = 0; i < CPW; i++) {
        const int rbase = (wave * CPW + i) * 8;
        if (rbase < BM) {
            gp[i] = A + (size_t)(bm + rbase + srow) * lda + scol;
            lp[i] = As + rbase * 64;
            stp[i] = stepA;
        } else {
            gp[i] = B + (size_t)(bn + (rbase - BM) + srow) * ldb + scol;
            lp[i] = Bs + (rbase - BM) * 64;
            stp[i] = stepB;
        }
    }

    const int mr = lane & 15;
    const int ko = lane >> 4;         // 0..3: k-chunk within a 32-wide MFMA

    for (int it = 0; it < kiters; it++) {
#pragma unroll
        for (int i = 0; i < CPW; i++)
            gl_lds16(gp[i] + (size_t)((long)it * stp[i]), lp[i]);
        __syncthreads();   // drains vmcnt; LDS tiles visible

        half8 af[MT][2], bf[NT][2];
#pragma unroll
        for (int kk = 0; kk < 2; kk++) {
            const int koff = ((ko + kk * 4) ^ (mr & 7)) * 8;  // swizzled
#pragma unroll
            for (int mt = 0; mt < MT; mt++)
                af[mt][kk] = *reinterpret_cast<const half8*>(
                    As + (wr * WM + mt * 16 + mr) * 64 + koff);
#pragma unroll
            for (int nt = 0; nt < NT; nt++)
                bf[nt][kk] = *reinterpret_cast<const half8*>(
                    Bs + (wc * WN + nt * 16 + mr) * 64 + koff);
        }
#pragma unroll
        for (int kk = 0; kk < 2; kk++)
#pragma unroll
            for (int mt = 0; mt < MT; mt++)
#pragma unroll
                for (int nt = 0; nt < NT; nt++)
                    acc[mt][nt] = __builtin_amdgcn_mfma_f32_16x16x32_f16(
                        af[mt][kk], bf[nt][kk], acc[mt][nt], 0, 0, 0);
        __syncthreads();   // all reads done before next stage overwrites
    }

    // Epilogue. C/D layout (verified m89): col = lane&15, row = quad*4+reg.
    const int rbase = (lane >> 4) * 4;
#pragma unroll
    for (int mt = 0; mt < MT; mt++) {
        const int row0 = bm + wr * WM + mt * 16 + rbase;
#pragma unroll
        for (int nt = 0; nt < NT; nt++) {
            const int col = bn + wc * WN + nt * 16 + mr;
#pragma unroll
            for (int r = 0; r < 4; r++) {
                float v = acc[mt][nt][r];
                if constexpr (EPI == 1) v = softplus_f(v + bias[col]);
                C[(size_t)(row0 + r) * ldc + col] = (OutT)v;
            }
        }
    }
}

// ---------------------------------------------------------------------------
// gemm3 split-K (BK=32, 64-B-row swizzle): x_dbl partials in F16 (halves
// partial write+read traffic; <=2e-4 rel rounding, under the absmax margin).
// A = u_h [4096][2048], B = W_xprojh [128][2048].  Grid (8, 32).
// Writes f16 partial [slice][4096][128].
// ---------------------------------------------------------------------------
__global__ __launch_bounds__(256) void gemm3_splitk(
    const f16* __restrict__ A, const f16* __restrict__ B,
    f16* __restrict__ Cp)
{
    __shared__ f16 As[128 * 32];
    __shared__ f16 Bs[128 * 32];

    const int tid  = threadIdx.x;
    const int lane = tid & 63;
    const int wave = tid >> 6;
    const int wr   = wave >> 1, wc = wave & 1;
    const int bm   = blockIdx.y * 128;
    const int kbeg = blockIdx.x * 256;

    floatx4 zero4 = {0.f, 0.f, 0.f, 0.f};
    floatx4 acc[4][4];
#pragma unroll
    for (int i = 0; i < 4; i++)
#pragma unroll
        for (int j = 0; j < 4; j++) acc[i][j] = zero4;

    const int srow = lane >> 2;
    const int scol = ((lane & 3) ^ ((srow >> 1) & 3)) * 8;
    const f16* gA0 = A + (size_t)(bm + wave * 32 + srow) * MB_DINNER + scol;
    const f16* gA1 = A + (size_t)(bm + wave * 32 + 16 + srow) * MB_DINNER + scol;
    const f16* gB0 = B + (size_t)(wave * 32 + srow) * MB_DINNER + scol;
    const f16* gB1 = B + (size_t)(wave * 32 + 16 + srow) * MB_DINNER + scol;
    f16* lA0 = As + wave * 1024;
    f16* lA1 = As + wave * 1024 + 512;
    f16* lB0 = Bs + wave * 1024;
    f16* lB1 = Bs + wave * 1024 + 512;

    const int mr = lane & 15;
    const int kq = ((lane >> 4) ^ ((mr >> 1) & 3)) * 8;

    for (int k0 = kbeg; k0 < kbeg + 256; k0 += 32) {
        gl_lds16(gA0 + k0, lA0);
        gl_lds16(gA1 + k0, lA1);
        gl_lds16(gB0 + k0, lB0);
        gl_lds16(gB1 + k0, lB1);
        __syncthreads();

        half8 af[4], bf[4];
#pragma unroll
        for (int mt = 0; mt < 4; mt++)
            af[mt] = *reinterpret_cast<const half8*>(
                As + (wr * 64 + mt * 16 + mr) * 32 + kq);
#pragma unroll
        for (int nt = 0; nt < 4; nt++)
            bf[nt] = *reinterpret_cast<const half8*>(
                Bs + (wc * 64 + nt * 16 + mr) * 32 + kq);
#pragma unroll
        for (int mt = 0; mt < 4; mt++)
#pragma unroll
            for (int nt = 0; nt < 4; nt++)
                acc[mt][nt] = __builtin_amdgcn_mfma_f32_16x16x32_f16(
                    af[mt], bf[nt], acc[mt][nt], 0, 0, 0);
        __syncthreads();
    }

    f16* Co = Cp + (size_t)blockIdx.x * MB_ROWS * 128;
    const int rbase = (lane >> 4) * 4;
#pragma unroll
    for (int mt = 0; mt < 4; mt++) {
        const int row0 = bm + wr * 64 + mt * 16 + rbase;
#pragma unroll
        for (int nt = 0; nt < 4; nt++) {
            const int col = wc * 64 + nt * 16 + mr;
#pragma unroll
            for (int r = 0; r < 4; r++)
                Co[(size_t)(row0 + r) * 128 + col] = (f16)acc[mt][nt][r];
        }
    }
}

// ---------------------------------------------------------------------------
// Reduce the 8 f16 split-K partials -> dt_h f16 [4096][64] (gemm4 A) and
// bc f32 [4096][32] (scan's B|C, compact rows).  98304 work items.
// ---------------------------------------------------------------------------
__global__ __launch_bounds__(256) void reduce_bc_kernel(
    const f16* __restrict__ Cp, f16* __restrict__ dt_h,
    float* __restrict__ bc)
{
    const int t = blockIdx.x * 256 + threadIdx.x;   // < 98304
    if (t < 65536) {
        const int row = t >> 4, c4 = (t & 15) * 4;  // dt cols 0..63
        float s[4] = {0.f, 0.f, 0.f, 0.f};
#pragma unroll
        for (int j = 0; j < 8; j++) {
            const half4 v = *reinterpret_cast<const half4*>(
                Cp + (size_t)j * MB_ROWS * 128 + (size_t)row * 128 + c4);
            s[0] += (float)v[0]; s[1] += (float)v[1];
            s[2] += (float)v[2]; s[3] += (float)v[3];
        }
        half4 h = {(f16)s[0], (f16)s[1], (f16)s[2], (f16)s[3]};
        *reinterpret_cast<half4*>(dt_h + (size_t)row * 64 + c4) = h;
    } else {
        const int t2 = t - 65536;
        const int row = t2 >> 3, c4 = (t2 & 7) * 4;  // bc cols 0..31 (=64..95)
        float4 s = {0.f, 0.f, 0.f, 0.f};
#pragma unroll
        for (int j = 0; j < 8; j++) {
            const half4 v = *reinterpret_cast<const half4*>(
                Cp + (size_t)j * MB_ROWS * 128 + (size_t)row * 128 + 64 + c4);
            s.x += (float)v[0]; s.y += (float)v[1];
            s.z += (float)v[2]; s.w += (float)v[3];
        }
        *reinterpret_cast<float4*>(bc + (size_t)row * 32 + c4) = s;
    }
}

// ---------------------------------------------------------------------------
// Causal depthwise conv1d (width 4) + bias + SiLU, sliding-window.
// Each thread: 8 channels x CV_R consecutive time-steps.
// ---------------------------------------------------------------------------
__global__ __launch_bounds__(256) void conv_silu_kernel(
    const f16* __restrict__ xz, const float* __restrict__ cw,
    const float* __restrict__ cb, f16* __restrict__ u)
{
    const int tid  = threadIdx.x;
    const int dv   = tid * 8;                 // channel base 0..2040
    const int rbeg = blockIdx.x * CV_R;       // global row base
    const int l0   = rbeg & (MB_L - 1);       // position within batch

    float wt[8][4];
#pragma unroll
    for (int j = 0; j < 8; j++) {
        const float4 wv = *reinterpret_cast<const float4*>(cw + (dv + j) * 4);
        wt[j][0] = wv.x; wt[j][1] = wv.y; wt[j][2] = wv.z; wt[j][3] = wv.w;
    }
    float bias[8];
    {
        const float4 b0 = *reinterpret_cast<const float4*>(cb + dv);
        const float4 b1 = *reinterpret_cast<const float4*>(cb + dv + 4);
        bias[0] = b0.x; bias[1] = b0.y; bias[2] = b0.z; bias[3] = b0.w;
        bias[4] = b1.x; bias[5] = b1.y; bias[6] = b1.z; bias[7] = b1.w;
    }

    half8 xr[CV_R + 3];
#pragma unroll
    for (int i = 0; i < 3; i++) {
        if (l0 >= 3 - i) {
            xr[i] = *reinterpret_cast<const half8*>(
                xz + (size_t)(rbeg - 3 + i) * MB_E2 + dv);
        } else {
#pragma unroll
            for (int j = 0; j < 8; j++) xr[i][j] = (f16)0.f;
        }
    }
#pragma unroll
    for (int r = 0; r < CV_R; r++)
        xr[3 + r] = *reinterpret_cast<const half8*>(
            xz + (size_t)(rbeg + r) * MB_E2 + dv);

#pragma unroll
    for (int r = 0; r < CV_R; r++) {
        float acc[8];
#pragma unroll
        for (int j = 0; j < 8; j++) acc[j] = bias[j];
#pragma unroll
        for (int k = 0; k < 4; k++) {
            const half8 xv = xr[r + k];
#pragma unroll
            for (int j = 0; j < 8; j++)
                acc[j] = fmaf((float)xv[j], wt[j][k], acc[j]);
        }
        half8 o;
#pragma unroll
        for (int j = 0; j < 8; j++) o[j] = (f16)silu_f(acc[j]);
        *reinterpret_cast<half8*>(u + (size_t)(rbeg + r) * MB_DINNER + dv) = o;
    }
}

// ---------------------------------------------------------------------------
// Scan pass 1 (v4): block = 64 channels x 64-step chunk, f16 LDS staging.
// Lane (ch, q): ch = wave*16 + (lane>>2)&15, q = lane&3 owns states 4q..4q+3.
// ---------------------------------------------------------------------------
__global__ __launch_bounds__(256) void scan_pass1(
    const f16*  __restrict__ delta,   // [4096][2048]
    const f16*  __restrict__ u,       // [4096][2048]
    const float* __restrict__ bc,     // [4096][32]  (B|C compact)
    const float* __restrict__ A_log,  // [2048][16]
    float* __restrict__ Hc,           // [32][4096][16]
    float* __restrict__ Pc)           // [32][4096][16]
{
    __shared__ half2v sDU[SC_CB][SC_CL + 2];   // (δ, δ·u)  [ch][step], f16
    __shared__ float  sB[SC_CL][20];           // B  [step][n], +4 pad

    const int tid   = threadIdx.x;
    const int lane  = tid & 63;
    const int wave  = tid >> 6;
    const int cg    = (lane >> 2) & 15;
    const int q     = lane & 3;
    const int ch    = wave * 16 + cg;          // channel in block, 0..63
    const int cb    = blockIdx.x & 63;
    const int chunk = blockIdx.x >> 6;
    const int gchan = cb * SC_CB + ch;
    const int b     = gchan >> 11;
    const int dbase = (cb & 31) * SC_CB;
    const int d     = dbase + ch;
    const int lbeg  = chunk * SC_CHUNK;

    const size_t base2048 = (size_t)b * MB_L * MB_DINNER;
    const size_t baseBC   = (size_t)b * MB_L * 32;

    const float4 alog = *reinterpret_cast<const float4*>(
        A_log + d * MB_DSTATE + q * 4);
    float Av2[4] = {-expf(alog.x) * 1.44269504f, -expf(alog.y) * 1.44269504f,
                    -expf(alog.z) * 1.44269504f, -expf(alog.w) * 1.44269504f};
    float h[4] = {0.f, 0.f, 0.f, 0.f};
    float sdt = 0.f;

    const int lloc  = tid >> 3;        // 0..31
    const int c8    = (tid & 7) * 8;   // 0..56
    const int cpair = (tid & 7) * 2;   // 0..14

    half8 pD, pU; float2 pB;
    auto stage_load = [&](int l0) {
        const size_t row = (size_t)(l0 + lloc);
        pD = *reinterpret_cast<const half8*>(
            delta + base2048 + row * MB_DINNER + dbase + c8);
        pU = *reinterpret_cast<const half8*>(
            u + base2048 + row * MB_DINNER + dbase + c8);
        pB = *reinterpret_cast<const float2*>(bc + baseBC + row * 32 + cpair);
    };
    auto stage_write = [&]() {
#pragma unroll
        for (int j = 0; j < 8; j++) {
            half2v t; t[0] = pD[j]; t[1] = pD[j] * pU[j];
            sDU[c8 + j][lloc] = t;
        }
        *reinterpret_cast<float2*>(&sB[lloc][cpair]) = pB;
    };

    stage_load(lbeg);
    stage_write();
    __syncthreads();

    for (int l0 = lbeg; l0 < lbeg + SC_CHUNK; l0 += SC_CL) {
        const bool has_next = (l0 + SC_CL) < lbeg + SC_CHUNK;
        if (has_next) stage_load(l0 + SC_CL);

#pragma unroll
        for (int ll = 0; ll < SC_CL; ll++) {
            const half2v duh = sDU[ch][ll];
            const float dx = (float)duh[0], dy = (float)duh[1];
            const float4 Bv = *reinterpret_cast<const float4*>(&sB[ll][q * 4]);
            h[0] = fmaf(exp2_fast(dx * Av2[0]), h[0], dy * Bv.x);
            h[1] = fmaf(exp2_fast(dx * Av2[1]), h[1], dy * Bv.y);
            h[2] = fmaf(exp2_fast(dx * Av2[2]), h[2], dy * Bv.z);
            h[3] = fmaf(exp2_fast(dx * Av2[3]), h[3], dy * Bv.w);
            sdt += dx;
        }
        __syncthreads();
        if (has_next) stage_write();
        __syncthreads();
    }

    const size_t cidx = ((size_t)chunk * MB_ROWS + gchan) * MB_DSTATE + q * 4;
    float4 H4 = {h[0], h[1], h[2], h[3]};
    float4 P4 = {exp2_fast(Av2[0] * sdt), exp2_fast(Av2[1] * sdt),
                 exp2_fast(Av2[2] * sdt), exp2_fast(Av2[3] * sdt)};
    *reinterpret_cast<float4*>(Hc + cidx) = H4;
    *reinterpret_cast<float4*>(Pc + cidx) = P4;
}

// ---------------------------------------------------------------------------
// Scan pass 2 (v4): carry-combine (float4 H/P per lane, <=31 fma), replay
// chunk.  f16 LDS staging.
// ---------------------------------------------------------------------------
__global__ __launch_bounds__(256) void scan_pass2(
    const f16*  __restrict__ delta,   // [4096][2048]
    const f16*  __restrict__ u,       // [4096][2048]
    const float* __restrict__ bc,     // [4096][32]  (B|C compact)
    const float* __restrict__ A_log,  // [2048][16]
    const float* __restrict__ Dskip,  // [2048]
    const f16*  __restrict__ xz,      // z = cols [2048,4096)
    const float* __restrict__ Hc,     // [32][4096][16]
    const float* __restrict__ Pc,     // [32][4096][16]
    f16* __restrict__ yg)             // [4096][2048]
{
    __shared__ half2v sDU[SC_CB][SC_CL + 2];   // (δ, δ·u)  f16
    __shared__ half2v sGS[SC_CB][SC_CL + 2];   // (g, u·Dsk·g)  f16
    __shared__ float  sB[SC_CL][20];
    __shared__ float  sC[SC_CL][20];

    const int tid   = threadIdx.x;
    const int lane  = tid & 63;
    const int wave  = tid >> 6;
    const int cg    = (lane >> 2) & 15;
    const int q     = lane & 3;
    const int ch    = wave * 16 + cg;
    const int cb    = blockIdx.x & 63;
    const int chunk = blockIdx.x >> 6;
    const int gchan = cb * SC_CB + ch;
    const int b     = gchan >> 11;
    const int dbase = (cb & 31) * SC_CB;
    const int d     = dbase + ch;
    const int lbeg  = chunk * SC_CHUNK;

    const size_t base2048 = (size_t)b * MB_L * MB_DINNER;
    const size_t base4096 = (size_t)b * MB_L * MB_E2;
    const size_t baseBC   = (size_t)b * MB_L * 32;

    const float4 alog = *reinterpret_cast<const float4*>(
        A_log + d * MB_DSTATE + q * 4);
    float Av2[4] = {-expf(alog.x) * 1.44269504f, -expf(alog.y) * 1.44269504f,
                    -expf(alog.z) * 1.44269504f, -expf(alog.w) * 1.44269504f};

    const int lloc  = tid >> 3;
    const int c8    = (tid & 7) * 8;
    const int cpair = (tid & 7) * 2;

    float Dsk8[8];
    {
        const float4 d0 = *reinterpret_cast<const float4*>(Dskip + dbase + c8);
        const float4 d1 = *reinterpret_cast<const float4*>(Dskip + dbase + c8 + 4);
        Dsk8[0] = d0.x; Dsk8[1] = d0.y; Dsk8[2] = d0.z; Dsk8[3] = d0.w;
        Dsk8[4] = d1.x; Dsk8[5] = d1.y; Dsk8[6] = d1.z; Dsk8[7] = d1.w;
    }

    half8 pD, pU, pZ; float2 pB, pC;
    auto stage_load = [&](int l0) {
        const size_t row = (size_t)(l0 + lloc);
        pD = *reinterpret_cast<const half8*>(
            delta + base2048 + row * MB_DINNER + dbase + c8);
        pU = *reinterpret_cast<const half8*>(
            u + base2048 + row * MB_DINNER + dbase + c8);
        pZ = *reinterpret_cast<const half8*>(
            xz + base4096 + row * MB_E2 + MB_DINNER + dbase + c8);
        pB = *reinterpret_cast<const float2*>(bc + baseBC + row * 32 + cpair);
        pC = *reinterpret_cast<const float2*>(
            bc + baseBC + row * 32 + 16 + cpair);
    };
    auto stage_write = [&]() {
#pragma unroll
        for (int j = 0; j < 8; j++) {
            half2v t; t[0] = pD[j]; t[1] = pD[j] * pU[j];
            sDU[c8 + j][lloc] = t;
            const float uu = (float)pU[j];
            const float g = silu_f((float)pZ[j]);
            half2v gs; gs[0] = (f16)g; gs[1] = (f16)(uu * Dsk8[j] * g);
            sGS[c8 + j][lloc] = gs;
        }
        *reinterpret_cast<float2*>(&sB[lloc][cpair]) = pB;
        *reinterpret_cast<float2*>(&sC[lloc][cpair]) = pC;
    };

    stage_load(lbeg);   // issue first window's loads before the carry chain

    float h[4] = {0.f, 0.f, 0.f, 0.f};
    for (int j = 0; j < chunk; j++) {
        const size_t cidx = ((size_t)j * MB_ROWS + gchan) * MB_DSTATE + q * 4;
        const float4 P4 = *reinterpret_cast<const float4*>(Pc + cidx);
        const float4 H4 = *reinterpret_cast<const float4*>(Hc + cidx);
        h[0] = fmaf(P4.x, h[0], H4.x);
        h[1] = fmaf(P4.y, h[1], H4.y);
        h[2] = fmaf(P4.z, h[2], H4.z);
        h[3] = fmaf(P4.w, h[3], H4.w);
    }

    stage_write();
    __syncthreads();

    for (int l0 = lbeg; l0 < lbeg + SC_CHUNK; l0 += SC_CL) {
        const bool has_next = (l0 + SC_CL) < lbeg + SC_CHUNK;
        if (has_next) stage_load(l0 + SC_CL);

        float y[SC_CL / 4] = {0.f, 0.f, 0.f, 0.f, 0.f, 0.f, 0.f, 0.f};
#pragma unroll
        for (int ll = 0; ll < SC_CL; ll++) {
            const half2v duh = sDU[ch][ll];
            const float dx = (float)duh[0], dy = (float)duh[1];
            const float4 Bv = *reinterpret_cast<const float4*>(&sB[ll][q * 4]);
            const float4 Cv = *reinterpret_cast<const float4*>(&sC[ll][q * 4]);
            h[0] = fmaf(exp2_fast(dx * Av2[0]), h[0], dy * Bv.x);
            h[1] = fmaf(exp2_fast(dx * Av2[1]), h[1], dy * Bv.y);
            h[2] = fmaf(exp2_fast(dx * Av2[2]), h[2], dy * Bv.z);
            h[3] = fmaf(exp2_fast(dx * Av2[3]), h[3], dy * Bv.w);
            float p = h[0] * Cv.x;
            p = fmaf(h[1], Cv.y, p);
            p = fmaf(h[2], Cv.z, p);
            p = fmaf(h[3], Cv.w, p);
            p = dpp_add<0xB1>(p);   // quad xor1
            p = dpp_add<0x4E>(p);   // quad xor2: all 4 lanes hold 16-state sum
            y[ll >> 2] = (q == (ll & 3)) ? p : y[ll >> 2];
        }

#pragma unroll
        for (int k = 0; k < SC_CL / 4; k++) {
            const half2v gs = sGS[ch][4 * k + q];
            yg[base2048 + (size_t)(l0 + 4 * k + q) * MB_DINNER + dbase + ch] =
                (f16)fmaf(y[k], (float)gs[0], (float)gs[1]);
        }

        __syncthreads();
        if (has_next) stage_write();
        __syncthreads();
    }
}

// ---------------------------------------------------------------------------
extern "C" void kernel_launch(void* const* d_in, const int* in_sizes, int n_in,
                              void* d_out, int out_size, void* d_ws,
                              size_t ws_size, hipStream_t stream)
{
    const float* x      = (const float*)d_in[0];  // (2,2048,1024)
    const float* W_in   = (const float*)d_in[1];  // (4096,1024)
    const float* conv_w = (const float*)d_in[2];  // (2048,1,4)
    const float* conv_b = (const float*)d_in[3];  // (2048)
    const float* W_xproj= (const float*)d_in[4];  // (96,2048)
    const float* W_dt   = (const float*)d_in[5];  // (2048,64)
    const float* b_dt   = (const float*)d_in[6];  // (2048)
    const float* A_log  = (const float*)d_in[7];  // (2048,16)
    const float* Dskip  = (const float*)d_in[8];  // (2048)
    const float* W_out  = (const float*)d_in[9];  // (1024,2048)
    float* out = (float*)d_out;                   // (2,2048,1024)

    // Workspace (~129 MB).  The five f16 convert destinations
    // (x_h..W_outh) are CONTIGUOUS for the fused convert.
    char* p = (char*)d_ws;
    f16* xz_h    = (f16*)p;  p += (size_t)MB_ROWS * MB_E2 * 2;      // 33.6 MB
    f16* u_h     = (f16*)p;  p += (size_t)MB_ROWS * MB_DINNER * 2;  // 16.8 MB
    f16* delta_h = (f16*)p;  p += (size_t)MB_ROWS * MB_DINNER * 2;  // 16.8 MB
    f16* yg_h    = (f16*)p;  p += (size_t)MB_ROWS * MB_DINNER * 2;  // 16.8 MB
    f16* x_h     = (f16*)p;  p += (size_t)MB_ROWS * MB_DMODEL * 2;  // 8.4 MB
    f16* W_inh   = (f16*)p;  p += (size_t)MB_E2 * MB_DMODEL * 2;    // 8.4 MB
    f16* W_xprojh= (f16*)p;  p += (size_t)128 * MB_DINNER * 2;      // 0.5 MB
    f16* W_dth   = (f16*)p;  p += (size_t)MB_DINNER * MB_DTRANK * 2;// 0.26 MB
    f16* W_outh  = (f16*)p;  p += (size_t)MB_DMODEL * MB_DINNER * 2;// 4.2 MB
    f16* Cp_h    = (f16*)p;  p += (size_t)8 * MB_ROWS * 128 * 2;    // 8.4 MB
    f16* dt_h    = (f16*)p;  p += (size_t)MB_ROWS * 64 * 2;         // 0.5 MB
    float* bc    = (float*)p; p += (size_t)MB_ROWS * 32 * 4;        // 0.5 MB
    float* Hc    = (float*)p; p += (size_t)SC_NC * MB_ROWS * MB_DSTATE * 4; // 8.4 MB
    float* Pc    = (float*)p;                                       // 8.4 MB

    const dim3 blk(256);

    // 0) one fused fp32 -> f16 convert over all segments
    convert_all_kernel<<<5312, blk, 0, stream>>>(
        x, W_in, W_xproj, W_dt, W_out, x_h);

    // 1) xz = x @ W_in^T  (M=4096, N=4096, K=1024) -> f16.  1D grid with
    //    XCD-cluster decode: XCD j owns 4 contiguous M-tiles x all N-tiles.
    gemm_mfma<f16, 0, 128, 2, 2><<<1024, blk, 0, stream>>>(
        x_h, MB_DMODEL, W_inh, MB_DMODEL, xz_h, MB_E2, 16, 64, 64, nullptr);

    // 2) u = silu(causal_dwconv(xb) + conv_b), 8 ch x 4 rows/thread
    conv_silu_kernel<<<MB_ROWS / CV_R, blk, 0, stream>>>(
        xz_h, conv_w, conv_b, u_h);

    // 3) x_dbl = u @ W_xproj^T  (M=4096, N=128, K=2048), split-K x8 (f16
    //    partials) + compact reduce -> dt_h (gemm4 A) and bc (scan B|C)
    gemm3_splitk<<<dim3(8, 32), blk, 0, stream>>>(u_h, W_xprojh, Cp_h);
    reduce_bc_kernel<<<384, blk, 0, stream>>>(Cp_h, dt_h, bc);

    // 4) delta = softplus(dt_low @ W_dt^T + b_dt)  (M=4096, N=2048, K=64)
    //    single BK=64 iteration on the compact dt array (lda=64)
    gemm_mfma<f16, 1, 128, 2, -1><<<dim3(16, 32), blk, 0, stream>>>(
        dt_h, 64, W_dth, MB_DTRANK, delta_h, MB_DINNER, 1, 64, 64, b_dt);

    // 5a) scan pass 1: per-chunk (H, P) summaries (last chunk skipped)
    scan_pass1<<<(SC_NC - 1) * 64, blk, 0, stream>>>(
        delta_h, u_h, bc, A_log, Hc, Pc);

    // 5b) scan pass 2: carry-combine + replay with y/skip/gate -> yg (f16)
    scan_pass2<<<SC_NC * 64, blk, 0, stream>>>(
        delta_h, u_h, bc, A_log, Dskip, xz_h, Hc, Pc, yg_h);

    // 6) out = yg @ W_out^T   (M=4096, N=1024, K=2048) -> f32, 32 K-iters
    gemm_mfma<float, 0, 64, 4, -1><<<dim3(8, 64), blk, 0, stream>>>(
        yg_h, MB_DINNER, W_outh, MB_DINNER, out, MB_DMODEL, 32, 64, 64,
        nullptr);
}

// Round 14
// 308.844 us; speedup vs baseline: 1.0248x; 1.0248x over previous
//
#include <hip/hip_runtime.h>
#include <math.h>

// Mamba block fwd: B=2, L=2048, d_model=1024, d_inner=2048, d_state=16,
// d_conv=4, dt_rank=64.  GEMMs in f16 MFMA, scan fp32 chunked 2-pass.
// Round 14: revert round-13's XCD-cluster decode + runtime-stride K-walk
// (FETCH unchanged, dur regressed); keep f16 split-K partials + compact
// dt/bc reduce.
#define MB_B      2
#define MB_L      2048
#define MB_DMODEL 1024
#define MB_DINNER 2048
#define MB_DSTATE 16
#define MB_DTRANK 64
#define MB_ROWS   (MB_B * MB_L)      // 4096
#define MB_E2     (2 * MB_DINNER)    // 4096
#define SC_NC     32                 // scan chunks
#define SC_CHUNK  (MB_L / SC_NC)     // 64 steps per chunk
#define SC_CL     32                 // staging window (steps)
#define SC_CB     64                 // channels per scan block
#define CV_R      4                  // conv rows per thread

typedef _Float16 f16;
typedef __attribute__((ext_vector_type(2))) _Float16 half2v;
typedef __attribute__((ext_vector_type(4))) _Float16 half4;
typedef __attribute__((ext_vector_type(8))) _Float16 half8;
typedef __attribute__((ext_vector_type(4))) float floatx4;

__device__ __forceinline__ float softplus_f(float x) {
    return (x > 20.f) ? x : log1pf(expf(x));
}
__device__ __forceinline__ float silu_f(float x) {
    return x / (1.f + expf(-x));
}

#if __has_builtin(__builtin_amdgcn_exp2f)
__device__ __forceinline__ float exp2_fast(float x) {
    return __builtin_amdgcn_exp2f(x);
}
#else
__device__ __forceinline__ float exp2_fast(float x) {
    return __expf(0.69314718056f * x);
}
#endif

// async global->LDS, 16B/lane. LDS dst is WAVE-UNIFORM base; HW adds lane*16.
typedef const __attribute__((address_space(1))) unsigned char gbyte;
typedef __attribute__((address_space(3))) unsigned char lbyte;
__device__ __forceinline__ void gl_lds16(const void* g, void* l) {
    __builtin_amdgcn_global_load_lds((gbyte*)g, (lbyte*)l, 16, 0, 0);
}

// VALU cross-lane add via DPP.  0xB1 = quad xor1, 0x4E = quad xor2.
template <int CTRL>
__device__ __forceinline__ float dpp_add(float x) {
    int xi = __builtin_bit_cast(int, x);
    int yi = __builtin_amdgcn_update_dpp(0, xi, CTRL, 0xF, 0xF, true);
    return x + __builtin_bit_cast(float, yi);
}

// ---------------------------------------------------------------------------
// Single fused fp32 -> f16 convert over all weight/activation segments.
// ---------------------------------------------------------------------------
__global__ __launch_bounds__(256) void convert_all_kernel(
    const float* __restrict__ x, const float* __restrict__ W_in,
    const float* __restrict__ W_xproj, const float* __restrict__ W_dt,
    const float* __restrict__ W_out, f16* __restrict__ dst)
{
    const int i = (blockIdx.x * 256 + threadIdx.x) * 8;  // < 10878976
    const float* src;
    int local, nsrc;
    if (i < 4194304)      { src = x;       local = i;           nsrc = 4194304; }
    else if (i < 8388608) { src = W_in;    local = i - 4194304; nsrc = 4194304; }
    else if (i < 8650752) { src = W_xproj; local = i - 8388608; nsrc = 196608; }
    else if (i < 8781824) { src = W_dt;    local = i - 8650752; nsrc = 131072; }
    else                  { src = W_out;   local = i - 8781824; nsrc = 2097152; }
    half8 o;
    if (local < nsrc) {
        const float4 a = *reinterpret_cast<const float4*>(src + local);
        const float4 b = *reinterpret_cast<const float4*>(src + local + 4);
        o[0] = (f16)a.x; o[1] = (f16)a.y; o[2] = (f16)a.z; o[3] = (f16)a.w;
        o[4] = (f16)b.x; o[5] = (f16)b.y; o[6] = (f16)b.z; o[7] = (f16)b.w;
    } else {
#pragma unroll
        for (int j = 0; j < 8; j++) o[j] = (f16)0.f;
    }
    *reinterpret_cast<half8*>(dst + i) = o;
}

// ---------------------------------------------------------------------------
// f16 MFMA GEMM, BK=64:  C[m][n] = sum_k A[m][k]*B[n][k]  (C = A·B^T)
// Block tile BM x 128, 4 waves in (4/GN) x GN grid.  XOR swizzle (128-B
// rows): global k-chunk g at stored position p obeys g = p ^ (row&7).
// EPI==1: v = softplus(v + bias[n]).
// ---------------------------------------------------------------------------
template <typename OutT, int EPI, int BM, int GN>
__global__ __launch_bounds__(256) void gemm_mfma(
    const f16* __restrict__ A, int lda,
    const f16* __restrict__ B, int ldb,
    OutT* __restrict__ C, int ldc, int K,
    const float* __restrict__ bias)
{
    constexpr int BN = 128;
    constexpr int GM = 4 / GN;
    constexpr int WM = BM / GM;       // wave tile rows
    constexpr int WN = BN / GN;       // wave tile cols
    constexpr int MT = WM / 16, NT = WN / 16;
    constexpr int CPW = (BM + BN) / 32;   // 8-row staging chunks per wave

    __shared__ f16 As[BM * 64];   // [row][k], row stride 64 halves (128 B)
    __shared__ f16 Bs[BN * 64];

    const int tid  = threadIdx.x;
    const int lane = tid & 63;
    const int wave = tid >> 6;
    const int wr   = wave / GN, wc = wave % GN;
    const int bm   = blockIdx.y * BM, bn = blockIdx.x * BN;

    floatx4 zero4 = {0.f, 0.f, 0.f, 0.f};
    floatx4 acc[MT][NT];
#pragma unroll
    for (int i = 0; i < MT; i++)
#pragma unroll
        for (int j = 0; j < NT; j++) acc[i][j] = zero4;

    const int srow = lane >> 3;
    const int scol = ((lane & 7) ^ (srow & 7)) * 8;
    const f16* gp[CPW];
    f16* lp[CPW];
#pragma unroll
    for (int i = 0; i < CPW; i++) {
        const int rbase = (wave * CPW + i) * 8;
        if (rbase < BM) {
            gp[i] = A + (size_t)(bm + rbase + srow) * lda + scol;
            lp[i] = As + rbase * 64;
        } else {
            gp[i] = B + (size_t)(bn + (rbase - BM) + srow) * ldb + scol;
            lp[i] = Bs + (rbase - BM) * 64;
        }
    }

    const int mr = lane & 15;
    const int ko = lane >> 4;         // 0..3: k-chunk within a 32-wide MFMA

    for (int k0 = 0; k0 < K; k0 += 64) {
#pragma unroll
        for (int i = 0; i < CPW; i++) gl_lds16(gp[i] + k0, lp[i]);
        __syncthreads();   // drains vmcnt; LDS tiles visible

        half8 af[MT][2], bf[NT][2];
#pragma unroll
        for (int kk = 0; kk < 2; kk++) {
            const int koff = ((ko + kk * 4) ^ (mr & 7)) * 8;  // swizzled
#pragma unroll
            for (int mt = 0; mt < MT; mt++)
                af[mt][kk] = *reinterpret_cast<const half8*>(
                    As + (wr * WM + mt * 16 + mr) * 64 + koff);
#pragma unroll
            for (int nt = 0; nt < NT; nt++)
                bf[nt][kk] = *reinterpret_cast<const half8*>(
                    Bs + (wc * WN + nt * 16 + mr) * 64 + koff);
        }
#pragma unroll
        for (int kk = 0; kk < 2; kk++)
#pragma unroll
            for (int mt = 0; mt < MT; mt++)
#pragma unroll
                for (int nt = 0; nt < NT; nt++)
                    acc[mt][nt] = __builtin_amdgcn_mfma_f32_16x16x32_f16(
                        af[mt][kk], bf[nt][kk], acc[mt][nt], 0, 0, 0);
        __syncthreads();   // all reads done before next stage overwrites
    }

    // Epilogue. C/D layout (verified m89): col = lane&15, row = quad*4+reg.
    const int rbase = (lane >> 4) * 4;
#pragma unroll
    for (int mt = 0; mt < MT; mt++) {
        const int row0 = bm + wr * WM + mt * 16 + rbase;
#pragma unroll
        for (int nt = 0; nt < NT; nt++) {
            const int col = bn + wc * WN + nt * 16 + mr;
#pragma unroll
            for (int r = 0; r < 4; r++) {
                float v = acc[mt][nt][r];
                if constexpr (EPI == 1) v = softplus_f(v + bias[col]);
                C[(size_t)(row0 + r) * ldc + col] = (OutT)v;
            }
        }
    }
}

// ---------------------------------------------------------------------------
// gemm3 split-K (BK=32, 64-B-row swizzle): x_dbl partials in F16 (halves
// partial write+read traffic; <=2e-4 rel rounding, under the absmax margin).
// A = u_h [4096][2048], B = W_xprojh [128][2048].  Grid (8, 32).
// Writes f16 partial [slice][4096][128].
// ---------------------------------------------------------------------------
__global__ __launch_bounds__(256) void gemm3_splitk(
    const f16* __restrict__ A, const f16* __restrict__ B,
    f16* __restrict__ Cp)
{
    __shared__ f16 As[128 * 32];
    __shared__ f16 Bs[128 * 32];

    const int tid  = threadIdx.x;
    const int lane = tid & 63;
    const int wave = tid >> 6;
    const int wr   = wave >> 1, wc = wave & 1;
    const int bm   = blockIdx.y * 128;
    const int kbeg = blockIdx.x * 256;

    floatx4 zero4 = {0.f, 0.f, 0.f, 0.f};
    floatx4 acc[4][4];
#pragma unroll
    for (int i = 0; i < 4; i++)
#pragma unroll
        for (int j = 0; j < 4; j++) acc[i][j] = zero4;

    const int srow = lane >> 2;
    const int scol = ((lane & 3) ^ ((srow >> 1) & 3)) * 8;
    const f16* gA0 = A + (size_t)(bm + wave * 32 + srow) * MB_DINNER + scol;
    const f16* gA1 = A + (size_t)(bm + wave * 32 + 16 + srow) * MB_DINNER + scol;
    const f16* gB0 = B + (size_t)(wave * 32 + srow) * MB_DINNER + scol;
    const f16* gB1 = B + (size_t)(wave * 32 + 16 + srow) * MB_DINNER + scol;
    f16* lA0 = As + wave * 1024;
    f16* lA1 = As + wave * 1024 + 512;
    f16* lB0 = Bs + wave * 1024;
    f16* lB1 = Bs + wave * 1024 + 512;

    const int mr = lane & 15;
    const int kq = ((lane >> 4) ^ ((mr >> 1) & 3)) * 8;

    for (int k0 = kbeg; k0 < kbeg + 256; k0 += 32) {
        gl_lds16(gA0 + k0, lA0);
        gl_lds16(gA1 + k0, lA1);
        gl_lds16(gB0 + k0, lB0);
        gl_lds16(gB1 + k0, lB1);
        __syncthreads();

        half8 af[4], bf[4];
#pragma unroll
        for (int mt = 0; mt < 4; mt++)
            af[mt] = *reinterpret_cast<const half8*>(
                As + (wr * 64 + mt * 16 + mr) * 32 + kq);
#pragma unroll
        for (int nt = 0; nt < 4; nt++)
            bf[nt] = *reinterpret_cast<const half8*>(
                Bs + (wc * 64 + nt * 16 + mr) * 32 + kq);
#pragma unroll
        for (int mt = 0; mt < 4; mt++)
#pragma unroll
            for (int nt = 0; nt < 4; nt++)
                acc[mt][nt] = __builtin_amdgcn_mfma_f32_16x16x32_f16(
                    af[mt], bf[nt], acc[mt][nt], 0, 0, 0);
        __syncthreads();
    }

    f16* Co = Cp + (size_t)blockIdx.x * MB_ROWS * 128;
    const int rbase = (lane >> 4) * 4;
#pragma unroll
    for (int mt = 0; mt < 4; mt++) {
        const int row0 = bm + wr * 64 + mt * 16 + rbase;
#pragma unroll
        for (int nt = 0; nt < 4; nt++) {
            const int col = wc * 64 + nt * 16 + mr;
#pragma unroll
            for (int r = 0; r < 4; r++)
                Co[(size_t)(row0 + r) * 128 + col] = (f16)acc[mt][nt][r];
        }
    }
}

// ---------------------------------------------------------------------------
// Reduce the 8 f16 split-K partials -> dt_h f16 [4096][64] (gemm4 A) and
// bc f32 [4096][32] (scan's B|C, compact rows).  98304 work items.
// ---------------------------------------------------------------------------
__global__ __launch_bounds__(256) void reduce_bc_kernel(
    const f16* __restrict__ Cp, f16* __restrict__ dt_h,
    float* __restrict__ bc)
{
    const int t = blockIdx.x * 256 + threadIdx.x;   // < 98304
    if (t < 65536) {
        const int row = t >> 4, c4 = (t & 15) * 4;  // dt cols 0..63
        float s[4] = {0.f, 0.f, 0.f, 0.f};
#pragma unroll
        for (int j = 0; j < 8; j++) {
            const half4 v = *reinterpret_cast<const half4*>(
                Cp + (size_t)j * MB_ROWS * 128 + (size_t)row * 128 + c4);
            s[0] += (float)v[0]; s[1] += (float)v[1];
            s[2] += (float)v[2]; s[3] += (float)v[3];
        }
        half4 h = {(f16)s[0], (f16)s[1], (f16)s[2], (f16)s[3]};
        *reinterpret_cast<half4*>(dt_h + (size_t)row * 64 + c4) = h;
    } else {
        const int t2 = t - 65536;
        const int row = t2 >> 3, c4 = (t2 & 7) * 4;  // bc cols 0..31 (=64..95)
        float4 s = {0.f, 0.f, 0.f, 0.f};
#pragma unroll
        for (int j = 0; j < 8; j++) {
            const half4 v = *reinterpret_cast<const half4*>(
                Cp + (size_t)j * MB_ROWS * 128 + (size_t)row * 128 + 64 + c4);
            s.x += (float)v[0]; s.y += (float)v[1];
            s.z += (float)v[2]; s.w += (float)v[3];
        }
        *reinterpret_cast<float4*>(bc + (size_t)row * 32 + c4) = s;
    }
}

// ---------------------------------------------------------------------------
// Causal depthwise conv1d (width 4) + bias + SiLU, sliding-window.
// Each thread: 8 channels x CV_R consecutive time-steps.
// ---------------------------------------------------------------------------
__global__ __launch_bounds__(256) void conv_silu_kernel(
    const f16* __restrict__ xz, const float* __restrict__ cw,
    const float* __restrict__ cb, f16* __restrict__ u)
{
    const int tid  = threadIdx.x;
    const int dv   = tid * 8;                 // channel base 0..2040
    const int rbeg = blockIdx.x * CV_R;       // global row base
    const int l0   = rbeg & (MB_L - 1);       // position within batch

    float wt[8][4];
#pragma unroll
    for (int j = 0; j < 8; j++) {
        const float4 wv = *reinterpret_cast<const float4*>(cw + (dv + j) * 4);
        wt[j][0] = wv.x; wt[j][1] = wv.y; wt[j][2] = wv.z; wt[j][3] = wv.w;
    }
    float bias[8];
    {
        const float4 b0 = *reinterpret_cast<const float4*>(cb + dv);
        const float4 b1 = *reinterpret_cast<const float4*>(cb + dv + 4);
        bias[0] = b0.x; bias[1] = b0.y; bias[2] = b0.z; bias[3] = b0.w;
        bias[4] = b1.x; bias[5] = b1.y; bias[6] = b1.z; bias[7] = b1.w;
    }

    half8 xr[CV_R + 3];
#pragma unroll
    for (int i = 0; i < 3; i++) {
        if (l0 >= 3 - i) {
            xr[i] = *reinterpret_cast<const half8*>(
                xz + (size_t)(rbeg - 3 + i) * MB_E2 + dv);
        } else {
#pragma unroll
            for (int j = 0; j < 8; j++) xr[i][j] = (f16)0.f;
        }
    }
#pragma unroll
    for (int r = 0; r < CV_R; r++)
        xr[3 + r] = *reinterpret_cast<const half8*>(
            xz + (size_t)(rbeg + r) * MB_E2 + dv);

#pragma unroll
    for (int r = 0; r < CV_R; r++) {
        float acc[8];
#pragma unroll
        for (int j = 0; j < 8; j++) acc[j] = bias[j];
#pragma unroll
        for (int k = 0; k < 4; k++) {
            const half8 xv = xr[r + k];
#pragma unroll
            for (int j = 0; j < 8; j++)
                acc[j] = fmaf((float)xv[j], wt[j][k], acc[j]);
        }
        half8 o;
#pragma unroll
        for (int j = 0; j < 8; j++) o[j] = (f16)silu_f(acc[j]);
        *reinterpret_cast<half8*>(u + (size_t)(rbeg + r) * MB_DINNER + dv) = o;
    }
}

// ---------------------------------------------------------------------------
// Scan pass 1 (v4): block = 64 channels x 64-step chunk, f16 LDS staging.
// Lane (ch, q): ch = wave*16 + (lane>>2)&15, q = lane&3 owns states 4q..4q+3.
// ---------------------------------------------------------------------------
__global__ __launch_bounds__(256) void scan_pass1(
    const f16*  __restrict__ delta,   // [4096][2048]
    const f16*  __restrict__ u,       // [4096][2048]
    const float* __restrict__ bc,     // [4096][32]  (B|C compact)
    const float* __restrict__ A_log,  // [2048][16]
    float* __restrict__ Hc,           // [32][4096][16]
    float* __restrict__ Pc)           // [32][4096][16]
{
    __shared__ half2v sDU[SC_CB][SC_CL + 2];   // (δ, δ·u)  [ch][step], f16
    __shared__ float  sB[SC_CL][20];           // B  [step][n], +4 pad

    const int tid   = threadIdx.x;
    const int lane  = tid & 63;
    const int wave  = tid >> 6;
    const int cg    = (lane >> 2) & 15;
    const int q     = lane & 3;
    const int ch    = wave * 16 + cg;          // channel in block, 0..63
    const int cb    = blockIdx.x & 63;
    const int chunk = blockIdx.x >> 6;
    const int gchan = cb * SC_CB + ch;
    const int b     = gchan >> 11;
    const int dbase = (cb & 31) * SC_CB;
    const int d     = dbase + ch;
    const int lbeg  = chunk * SC_CHUNK;

    const size_t base2048 = (size_t)b * MB_L * MB_DINNER;
    const size_t baseBC   = (size_t)b * MB_L * 32;

    const float4 alog = *reinterpret_cast<const float4*>(
        A_log + d * MB_DSTATE + q * 4);
    float Av2[4] = {-expf(alog.x) * 1.44269504f, -expf(alog.y) * 1.44269504f,
                    -expf(alog.z) * 1.44269504f, -expf(alog.w) * 1.44269504f};
    float h[4] = {0.f, 0.f, 0.f, 0.f};
    float sdt = 0.f;

    const int lloc  = tid >> 3;        // 0..31
    const int c8    = (tid & 7) * 8;   // 0..56
    const int cpair = (tid & 7) * 2;   // 0..14

    half8 pD, pU; float2 pB;
    auto stage_load = [&](int l0) {
        const size_t row = (size_t)(l0 + lloc);
        pD = *reinterpret_cast<const half8*>(
            delta + base2048 + row * MB_DINNER + dbase + c8);
        pU = *reinterpret_cast<const half8*>(
            u + base2048 + row * MB_DINNER + dbase + c8);
        pB = *reinterpret_cast<const float2*>(bc + baseBC + row * 32 + cpair);
    };
    auto stage_write = [&]() {
#pragma unroll
        for (int j = 0; j < 8; j++) {
            half2v t; t[0] = pD[j]; t[1] = pD[j] * pU[j];
            sDU[c8 + j][lloc] = t;
        }
        *reinterpret_cast<float2*>(&sB[lloc][cpair]) = pB;
    };

    stage_load(lbeg);
    stage_write();
    __syncthreads();

    for (int l0 = lbeg; l0 < lbeg + SC_CHUNK; l0 += SC_CL) {
        const bool has_next = (l0 + SC_CL) < lbeg + SC_CHUNK;
        if (has_next) stage_load(l0 + SC_CL);

#pragma unroll
        for (int ll = 0; ll < SC_CL; ll++) {
            const half2v duh = sDU[ch][ll];
            const float dx = (float)duh[0], dy = (float)duh[1];
            const float4 Bv = *reinterpret_cast<const float4*>(&sB[ll][q * 4]);
            h[0] = fmaf(exp2_fast(dx * Av2[0]), h[0], dy * Bv.x);
            h[1] = fmaf(exp2_fast(dx * Av2[1]), h[1], dy * Bv.y);
            h[2] = fmaf(exp2_fast(dx * Av2[2]), h[2], dy * Bv.z);
            h[3] = fmaf(exp2_fast(dx * Av2[3]), h[3], dy * Bv.w);
            sdt += dx;
        }
        __syncthreads();
        if (has_next) stage_write();
        __syncthreads();
    }

    const size_t cidx = ((size_t)chunk * MB_ROWS + gchan) * MB_DSTATE + q * 4;
    float4 H4 = {h[0], h[1], h[2], h[3]};
    float4 P4 = {exp2_fast(Av2[0] * sdt), exp2_fast(Av2[1] * sdt),
                 exp2_fast(Av2[2] * sdt), exp2_fast(Av2[3] * sdt)};
    *reinterpret_cast<float4*>(Hc + cidx) = H4;
    *reinterpret_cast<float4*>(Pc + cidx) = P4;
}

// ---------------------------------------------------------------------------
// Scan pass 2 (v4): carry-combine (float4 H/P per lane, <=31 fma), replay
// chunk.  f16 LDS staging.
// ---------------------------------------------------------------------------
__global__ __launch_bounds__(256) void scan_pass2(
    const f16*  __restrict__ delta,   // [4096][2048]
    const f16*  __restrict__ u,       // [4096][2048]
    const float* __restrict__ bc,     // [4096][32]  (B|C compact)
    const float* __restrict__ A_log,  // [2048][16]
    const float* __restrict__ Dskip,  // [2048]
    const f16*  __restrict__ xz,      // z = cols [2048,4096)
    const float* __restrict__ Hc,     // [32][4096][16]
    const float* __restrict__ Pc,     // [32][4096][16]
    f16* __restrict__ yg)             // [4096][2048]
{
    __shared__ half2v sDU[SC_CB][SC_CL + 2];   // (δ, δ·u)  f16
    __shared__ half2v sGS[SC_CB][SC_CL + 2];   // (g, u·Dsk·g)  f16
    __shared__ float  sB[SC_CL][20];
    __shared__ float  sC[SC_CL][20];

    const int tid   = threadIdx.x;
    const int lane  = tid & 63;
    const int wave  = tid >> 6;
    const int cg    = (lane >> 2) & 15;
    const int q     = lane & 3;
    const int ch    = wave * 16 + cg;
    const int cb    = blockIdx.x & 63;
    const int chunk = blockIdx.x >> 6;
    const int gchan = cb * SC_CB + ch;
    const int b     = gchan >> 11;
    const int dbase = (cb & 31) * SC_CB;
    const int d     = dbase + ch;
    const int lbeg  = chunk * SC_CHUNK;

    const size_t base2048 = (size_t)b * MB_L * MB_DINNER;
    const size_t base4096 = (size_t)b * MB_L * MB_E2;
    const size_t baseBC   = (size_t)b * MB_L * 32;

    const float4 alog = *reinterpret_cast<const float4*>(
        A_log + d * MB_DSTATE + q * 4);
    float Av2[4] = {-expf(alog.x) * 1.44269504f, -expf(alog.y) * 1.44269504f,
                    -expf(alog.z) * 1.44269504f, -expf(alog.w) * 1.44269504f};

    const int lloc  = tid >> 3;
    const int c8    = (tid & 7) * 8;
    const int cpair = (tid & 7) * 2;

    float Dsk8[8];
    {
        const float4 d0 = *reinterpret_cast<const float4*>(Dskip + dbase + c8);
        const float4 d1 = *reinterpret_cast<const float4*>(Dskip + dbase + c8 + 4);
        Dsk8[0] = d0.x; Dsk8[1] = d0.y; Dsk8[2] = d0.z; Dsk8[3] = d0.w;
        Dsk8[4] = d1.x; Dsk8[5] = d1.y; Dsk8[6] = d1.z; Dsk8[7] = d1.w;
    }

    half8 pD, pU, pZ; float2 pB, pC;
    auto stage_load = [&](int l0) {
        const size_t row = (size_t)(l0 + lloc);
        pD = *reinterpret_cast<const half8*>(
            delta + base2048 + row * MB_DINNER + dbase + c8);
        pU = *reinterpret_cast<const half8*>(
            u + base2048 + row * MB_DINNER + dbase + c8);
        pZ = *reinterpret_cast<const half8*>(
            xz + base4096 + row * MB_E2 + MB_DINNER + dbase + c8);
        pB = *reinterpret_cast<const float2*>(bc + baseBC + row * 32 + cpair);
        pC = *reinterpret_cast<const float2*>(
            bc + baseBC + row * 32 + 16 + cpair);
    };
    auto stage_write = [&]() {
#pragma unroll
        for (int j = 0; j < 8; j++) {
            half2v t; t[0] = pD[j]; t[1] = pD[j] * pU[j];
            sDU[c8 + j][lloc] = t;
            const float uu = (float)pU[j];
            const float g = silu_f((float)pZ[j]);
            half2v gs; gs[0] = (f16)g; gs[1] = (f16)(uu * Dsk8[j] * g);
            sGS[c8 + j][lloc] = gs;
        }
        *reinterpret_cast<float2*>(&sB[lloc][cpair]) = pB;
        *reinterpret_cast<float2*>(&sC[lloc][cpair]) = pC;
    };

    stage_load(lbeg);   // issue first window's loads before the carry chain

    float h[4] = {0.f, 0.f, 0.f, 0.f};
    for (int j = 0; j < chunk; j++) {
        const size_t cidx = ((size_t)j * MB_ROWS + gchan) * MB_DSTATE + q * 4;
        const float4 P4 = *reinterpret_cast<const float4*>(Pc + cidx);
        const float4 H4 = *reinterpret_cast<const float4*>(Hc + cidx);
        h[0] = fmaf(P4.x, h[0], H4.x);
        h[1] = fmaf(P4.y, h[1], H4.y);
        h[2] = fmaf(P4.z, h[2], H4.z);
        h[3] = fmaf(P4.w, h[3], H4.w);
    }

    stage_write();
    __syncthreads();

    for (int l0 = lbeg; l0 < lbeg + SC_CHUNK; l0 += SC_CL) {
        const bool has_next = (l0 + SC_CL) < lbeg + SC_CHUNK;
        if (has_next) stage_load(l0 + SC_CL);

        float y[SC_CL / 4] = {0.f, 0.f, 0.f, 0.f, 0.f, 0.f, 0.f, 0.f};
#pragma unroll
        for (int ll = 0; ll < SC_CL; ll++) {
            const half2v duh = sDU[ch][ll];
            const float dx = (float)duh[0], dy = (float)duh[1];
            const float4 Bv = *reinterpret_cast<const float4*>(&sB[ll][q * 4]);
            const float4 Cv = *reinterpret_cast<const float4*>(&sC[ll][q * 4]);
            h[0] = fmaf(exp2_fast(dx * Av2[0]), h[0], dy * Bv.x);
            h[1] = fmaf(exp2_fast(dx * Av2[1]), h[1], dy * Bv.y);
            h[2] = fmaf(exp2_fast(dx * Av2[2]), h[2], dy * Bv.z);
            h[3] = fmaf(exp2_fast(dx * Av2[3]), h[3], dy * Bv.w);
            float p = h[0] * Cv.x;
            p = fmaf(h[1], Cv.y, p);
            p = fmaf(h[2], Cv.z, p);
            p = fmaf(h[3], Cv.w, p);
            p = dpp_add<0xB1>(p);   // quad xor1
            p = dpp_add<0x4E>(p);   // quad xor2: all 4 lanes hold 16-state sum
            y[ll >> 2] = (q == (ll & 3)) ? p : y[ll >> 2];
        }

#pragma unroll
        for (int k = 0; k < SC_CL / 4; k++) {
            const half2v gs = sGS[ch][4 * k + q];
            yg[base2048 + (size_t)(l0 + 4 * k + q) * MB_DINNER + dbase + ch] =
                (f16)fmaf(y[k], (float)gs[0], (float)gs[1]);
        }

        __syncthreads();
        if (has_next) stage_write();
        __syncthreads();
    }
}

// ---------------------------------------------------------------------------
extern "C" void kernel_launch(void* const* d_in, const int* in_sizes, int n_in,
                              void* d_out, int out_size, void* d_ws,
                              size_t ws_size, hipStream_t stream)
{
    const float* x      = (const float*)d_in[0];  // (2,2048,1024)
    const float* W_in   = (const float*)d_in[1];  // (4096,1024)
    const float* conv_w = (const float*)d_in[2];  // (2048,1,4)
    const float* conv_b = (const float*)d_in[3];  // (2048)
    const float* W_xproj= (const float*)d_in[4];  // (96,2048)
    const float* W_dt   = (const float*)d_in[5];  // (2048,64)
    const float* b_dt   = (const float*)d_in[6];  // (2048)
    const float* A_log  = (const float*)d_in[7];  // (2048,16)
    const float* Dskip  = (const float*)d_in[8];  // (2048)
    const float* W_out  = (const float*)d_in[9];  // (1024,2048)
    float* out = (float*)d_out;                   // (2,2048,1024)

    // Workspace (~129 MB).  The five f16 convert destinations
    // (x_h..W_outh) are CONTIGUOUS for the fused convert.
    char* p = (char*)d_ws;
    f16* xz_h    = (f16*)p;  p += (size_t)MB_ROWS * MB_E2 * 2;      // 33.6 MB
    f16* u_h     = (f16*)p;  p += (size_t)MB_ROWS * MB_DINNER * 2;  // 16.8 MB
    f16* delta_h = (f16*)p;  p += (size_t)MB_ROWS * MB_DINNER * 2;  // 16.8 MB
    f16* yg_h    = (f16*)p;  p += (size_t)MB_ROWS * MB_DINNER * 2;  // 16.8 MB
    f16* x_h     = (f16*)p;  p += (size_t)MB_ROWS * MB_DMODEL * 2;  // 8.4 MB
    f16* W_inh   = (f16*)p;  p += (size_t)MB_E2 * MB_DMODEL * 2;    // 8.4 MB
    f16* W_xprojh= (f16*)p;  p += (size_t)128 * MB_DINNER * 2;      // 0.5 MB
    f16* W_dth   = (f16*)p;  p += (size_t)MB_DINNER * MB_DTRANK * 2;// 0.26 MB
    f16* W_outh  = (f16*)p;  p += (size_t)MB_DMODEL * MB_DINNER * 2;// 4.2 MB
    f16* Cp_h    = (f16*)p;  p += (size_t)8 * MB_ROWS * 128 * 2;    // 8.4 MB
    f16* dt_h    = (f16*)p;  p += (size_t)MB_ROWS * 64 * 2;         // 0.5 MB
    float* bc    = (float*)p; p += (size_t)MB_ROWS * 32 * 4;        // 0.5 MB
    float* Hc    = (float*)p; p += (size_t)SC_NC * MB_ROWS * MB_DSTATE * 4; // 8.4 MB
    float* Pc    = (float*)p;                                       // 8.4 MB

    const dim3 blk(256);

    // 0) one fused fp32 -> f16 convert over all segments
    convert_all_kernel<<<5312, blk, 0, stream>>>(
        x, W_in, W_xproj, W_dt, W_out, x_h);

    // 1) xz = x @ W_in^T     (M=4096, N=4096, K=1024) -> f16, 16 K-iters
    gemm_mfma<f16, 0, 128, 2><<<dim3(32, 32), blk, 0, stream>>>(
        x_h, MB_DMODEL, W_inh, MB_DMODEL, xz_h, MB_E2, MB_DMODEL, nullptr);

    // 2) u = silu(causal_dwconv(xb) + conv_b), 8 ch x 4 rows/thread
    conv_silu_kernel<<<MB_ROWS / CV_R, blk, 0, stream>>>(
        xz_h, conv_w, conv_b, u_h);

    // 3) x_dbl = u @ W_xproj^T  (M=4096, N=128, K=2048), split-K x8 (f16
    //    partials) + compact reduce -> dt_h (gemm4 A) and bc (scan B|C)
    gemm3_splitk<<<dim3(8, 32), blk, 0, stream>>>(u_h, W_xprojh, Cp_h);
    reduce_bc_kernel<<<384, blk, 0, stream>>>(Cp_h, dt_h, bc);

    // 4) delta = softplus(dt_low @ W_dt^T + b_dt)  (M=4096, N=2048, K=64)
    //    single BK=64 iteration on the compact dt array (lda=64)
    gemm_mfma<f16, 1, 128, 2><<<dim3(16, 32), blk, 0, stream>>>(
        dt_h, 64, W_dth, MB_DTRANK, delta_h, MB_DINNER, MB_DTRANK, b_dt);

    // 5a) scan pass 1: per-chunk (H, P) summaries (last chunk skipped)
    scan_pass1<<<(SC_NC - 1) * 64, blk, 0, stream>>>(
        delta_h, u_h, bc, A_log, Hc, Pc);

    // 5b) scan pass 2: carry-combine + replay with y/skip/gate -> yg (f16)
    scan_pass2<<<SC_NC * 64, blk, 0, stream>>>(
        delta_h, u_h, bc, A_log, Dskip, xz_h, Hc, Pc, yg_h);

    // 6) out = yg @ W_out^T   (M=4096, N=1024, K=2048) -> f32, 32 K-iters
    gemm_mfma<float, 0, 64, 4><<<dim3(8, 64), blk, 0, stream>>>(
        yg_h, MB_DINNER, W_outh, MB_DINNER, out, MB_DMODEL, MB_DINNER,
        nullptr);
}